// Round 8
// baseline (174.056 us; speedup 1.0000x reference)
//
#include <hip/hip_runtime.h>
#include <math.h>

// R8: chain restructure on top of R7's ring core.
//  - gemm2 monolithic-K (RING=8, 52 steps) with fused bias+sigmoid+*cmr+
//    transpose epilogue -> final_k deleted, logits_p round-trip deleted.
//  - colmax merged into prep_k (independent leaves, one launch).
//  - gemm1 XCD-clustered block swizzle (B-fragment L2 reuse).
// 4 launches total; ~82 MB traffic.

// Problem constants
#define B64 64
#define IN_SH 10000
#define EXP_SH 53
#define HID 1500
#define NPAD1 1536
#define NBC 2048
#define K2 1553
#define KS1 20              // gemm1 K-chunks: 24 coltiles x 20 = 480 blocks
#define KST1 16             // 16 steps of 32 -> kchunk 512 (20*512=10240)
#define KST2 52             // gemm2 monolithic: 52 steps of 32 = 1664 >= 1553
#define CMCH 32
#define ACC1 (NPAD1 * 64)   // floats per gemm1 partial

using short8  = __attribute__((ext_vector_type(8))) short;
using floatx4 = __attribute__((ext_vector_type(4))) float;
using uintx4  = __attribute__((ext_vector_type(4))) unsigned int;

__device__ __forceinline__ unsigned short f2bf(float f) {
    unsigned u = __float_as_uint(f);
    u += 0x7fffu + ((u >> 16) & 1u);   // RNE
    return (unsigned short)(u >> 16);
}

// ---- async global->LDS staging (16B/lane; LDS dest = uniform base + lane*16)
typedef __attribute__((address_space(3))) void lds_v;
typedef __attribute__((address_space(1))) const void glb_v;
__device__ __forceinline__ void gll16(const float* g, float* l) {
    __builtin_amdgcn_global_load_lds((glb_v*)g, (lds_v*)l, 16, 0, 0);
}

// counted vmcnt with memory clobber (pins loads/LDS reads across it)
#define WVS(n) asm volatile("s_waitcnt vmcnt(" #n ")" ::: "memory")
template<int N> __device__ __forceinline__ void waitv() {
    if constexpr (N >= 44)      WVS(44);
    else if constexpr (N >= 40) WVS(40);
    else if constexpr (N >= 36) WVS(36);
    else if constexpr (N >= 32) WVS(32);
    else if constexpr (N >= 28) WVS(28);
    else if constexpr (N >= 24) WVS(24);
    else if constexpr (N >= 20) WVS(20);
    else if constexpr (N >= 16) WVS(16);
    else if constexpr (N >= 12) WVS(12);
    else if constexpr (N >= 10) WVS(10);
    else if constexpr (N >= 8)  WVS(8);
    else if constexpr (N >= 6)  WVS(6);
    else if constexpr (N >= 4)  WVS(4);
    else if constexpr (N >= 2)  WVS(2);
    else                        WVS(0);
}

// VMEM ops issued after STAGE(st)'s 2 glls, up to the wait at iter st.
// Emission: prologue S0..S(RING-1), B0, B1; body st: [S(st+RING)] [B(st+2)].
constexpr int after_ops(int KS, int RING, int st) {
    int n = 0;
    if (st < RING) {
        n += 2 * (RING - 1 - st) + 8;
        for (int k = 0; k < st; k++)
            n += (k + RING < KS ? 2 : 0) + (k + 2 < KS ? 4 : 0);
    } else {
        n += (st - RING + 2 < KS ? 4 : 0);
        for (int k = st - RING + 1; k < st; k++)
            n += (k + RING < KS ? 2 : 0) + (k + 2 < KS ? 4 : 0);
    }
    return n;
}

template<int KS, int RING, int ST>
__device__ __forceinline__ void gstep(
    const float* __restrict__ W, const unsigned short* __restrict__ bf,
    float* __restrict__ ldsw, floatx4 (&acc)[4], uintx4 (&bv)[3][4],
    unsigned wbase, unsigned stepInc, unsigned halfInc, unsigned maxoff,
    int q, int l15)
{
    if constexpr (ST < KS) {
        constexpr int AO = after_ops(KS, RING, ST);
        waitv<(AO > 6 ? AO - 6 : 0)>();              // slot ST data is in LDS
        const float* lb = ldsw + (ST % RING) * 512;
        short8 af;
        #pragma unroll
        for (int j = 0; j < 8; j++)
            af[j] = (short)f2bf(lb[(q * 8 + j) * 16 + l15]);
        if constexpr (ST + RING < KS) {              // re-stage slot
            unsigned o0 = wbase + (unsigned)(ST + RING) * stepInc;
            unsigned o1 = o0 + halfInc;
            if (o0 > maxoff) o0 = maxoff;
            if (o1 > maxoff) o1 = maxoff;
            gll16(W + o0, ldsw + ((ST + RING) % RING) * 512);
            gll16(W + o1, ldsw + ((ST + RING) % RING) * 512 + 256);
        }
        if constexpr (ST + 2 < KS) {                 // B prefetch distance 2
            #pragma unroll
            for (int s = 0; s < 4; s++)
                bv[(ST + 2) % 3][s] =
                    *(const uintx4*)(bf + (size_t)((ST + 2) * 4 + s) * 512);
        }
        #pragma unroll
        for (int s = 0; s < 4; s++) {
            short8 b8 = __builtin_bit_cast(short8, bv[ST % 3][s]);
            acc[s] = __builtin_amdgcn_mfma_f32_16x16x32_bf16(af, b8, acc[s], 0, 0, 0);
        }
        gstep<KS, RING, ST + 1>(W, bf, ldsw, acc, bv, wbase, stepInc, halfInc,
                                maxoff, q, l15);
    }
}

// Wave-scoped ring GEMM: 16 cols x KS*32 k-rows into acc. LDS ring of RING
// 2KB slots staged via global_load_lds; OOB by address clamp (garbage rows
// multiply zero-padded B fragments; garbage cols land in padding).
template<int KS, int RING>
__device__ __forceinline__ void gemm_ring(
    const float* __restrict__ W, const unsigned short* __restrict__ Bfc,
    floatx4 (&acc)[4], int ldw, unsigned maxoff, int n0, int k0,
    int lane, float* __restrict__ ldsw)
{
    const int q = lane >> 4, l15 = lane & 15;
    const int r = lane >> 2, c4 = (lane & 3) * 4;
    unsigned wbase = (unsigned)((k0 + r) * ldw + n0 + c4);
    const unsigned stepInc = 32u * (unsigned)ldw;
    const unsigned halfInc = 16u * (unsigned)ldw;

    #pragma unroll
    for (int st = 0; st < RING; st++) {              // prologue: RING stages
        unsigned o0 = wbase + (unsigned)st * stepInc;
        unsigned o1 = o0 + halfInc;
        if (o0 > maxoff) o0 = maxoff;
        if (o1 > maxoff) o1 = maxoff;
        gll16(W + o0, ldsw + st * 512);
        gll16(W + o1, ldsw + st * 512 + 256);
    }
    const unsigned short* bf = Bfc + (size_t)lane * 8;
    uintx4 bv[3][4];
    #pragma unroll
    for (int k = 0; k < 2; k++) {                    // B0, B1
        #pragma unroll
        for (int s = 0; s < 4; s++)
            bv[k][s] = *(const uintx4*)(bf + (size_t)(k * 4 + s) * 512);
    }
    #pragma unroll
    for (int s = 0; s < 4; s++) acc[s] = (floatx4){0.f, 0.f, 0.f, 0.f};

    gstep<KS, RING, 0>(W, bf, ldsw, acc, bv, wbase, stepInc, halfInc, maxoff, q, l15);
}

// Node 1: [0,320) build gosBf | [320,576) hpo colmax chunks
__global__ __launch_bounds__(256) void prep_k(
    const float* __restrict__ g, unsigned short* __restrict__ gosBf,
    const float* __restrict__ M, float* __restrict__ cm)
{
    int bi = blockIdx.x;
    if (bi < 320) {
        int t    = bi * 256 + threadIdx.x;   // [0, 81920)
        int lane = t & 63;
        int sgrp = (t >> 6) & 3;
        int step = t >> 8;                   // [0, 320)
        int q    = lane >> 4;
        int l15  = lane & 15;
        int b    = sgrp * 16 + l15;
        int k0   = step * 32 + q * 8;
        const float* p = g + (size_t)b * IN_SH + k0;
        unsigned int o[4];
        #pragma unroll
        for (int i = 0; i < 4; i++) {
            float lo = (k0 + 2 * i     < IN_SH) ? p[2 * i]     : 0.f;
            float hi = (k0 + 2 * i + 1 < IN_SH) ? p[2 * i + 1] : 0.f;
            o[i] = (unsigned)f2bf(lo) | ((unsigned)f2bf(hi) << 16);
        }
        uintx4 v; v.x = o[0]; v.y = o[1]; v.z = o[2]; v.w = o[3];
        *(uintx4*)(gosBf + (size_t)t * 8) = v;
    } else {
        int u  = bi - 320;                   // [0, 256)
        int j  = (u & 7) * 256 + threadIdx.x;
        int i0 = (u >> 3) * 64;
        float m = 0.0f;
        #pragma unroll 16
        for (int i = i0; i < i0 + 64; i++)
            m = fmaxf(m, M[(size_t)i * NBC + j]);
        cm[(u >> 3) * NBC + j] = m;
    }
}

// Node 2: GEMM1 partials (480 blocks, ring core, XCD-clustered by-chunks)
__global__ __launch_bounds__(256, 4) void gemm1_k(
    const float* __restrict__ W1, const unsigned short* __restrict__ gosBf,
    float* __restrict__ hpre_p)
{
    __shared__ float lds[4 * 2048];
    int bi  = blockIdx.x;                    // [0, 480)
    int swz = (bi & 7) * 60 + (bi >> 3);     // bijective (480 = 8*60): same-by
    int bx  = swz % 24;                      // blocks cluster on one XCD
    int by  = swz / 24;
    int wid = threadIdx.x >> 6;
    int lane = threadIdx.x & 63;
    floatx4 acc[4];
    gemm_ring<KST1, 4>(W1, gosBf + (size_t)by * (KST1 * 4) * 512, acc, HID,
                       (unsigned)(IN_SH * HID - 4),
                       bx * 64 + wid * 16, by * (KST1 * 32),
                       lane, lds + wid * 2048);
    int q = lane >> 4, l15 = lane & 15;
    int nrow = bx * 64 + wid * 16 + q * 4;
    float* pbuf = hpre_p + (size_t)by * ACC1;
    #pragma unroll
    for (int s = 0; s < 4; s++) {
        #pragma unroll
        for (int rr = 0; rr < 4; rr++)
            pbuf[(size_t)(nrow + rr) * 64 + s * 16 + l15] = acc[s][rr];
    }
}

// Node 3: [0,208) reduce 20 partials + bias + GELU + concat -> Xf (coalesced,
// 40 independent streams); [208,216) reduce cm -> cmr.
__global__ __launch_bounds__(256) void combine1(
    const float* __restrict__ hpre_p, const float* __restrict__ b1,
    const float* __restrict__ expx, unsigned short* __restrict__ Xf,
    const float* __restrict__ cm, float* __restrict__ cmr)
{
    int bi = blockIdx.x;
    if (bi < 208) {
        int idx = bi * 256 + threadIdx.x;        // [0, 53248)
        int b   = idx & 63;
        int n0  = (idx >> 6) * 2;                // even n in [0, 1664)
        float v[2];
        #pragma unroll
        for (int e = 0; e < 2; e++) {
            int n = n0 + e;
            float x = 0.f;
            if (n < HID) {
                const float* p = hpre_p + (size_t)n * 64 + b;
                float a0 = 0.f, a1 = 0.f, a2 = 0.f, a3 = 0.f;
                #pragma unroll
                for (int ks = 0; ks < KS1; ks += 4) {
                    a0 += p[(size_t)ks * ACC1];
                    a1 += p[(size_t)(ks + 1) * ACC1];
                    a2 += p[(size_t)(ks + 2) * ACC1];
                    a3 += p[(size_t)(ks + 3) * ACC1];
                }
                float s = b1[n] + ((a0 + a1) + (a2 + a3));
                x = 0.5f * s * (1.0f + erff(s * 0.70710678118654752f));
            } else if (n < HID + EXP_SH) {
                x = expx[b * EXP_SH + (n - HID)];
            }
            v[e] = x;
        }
        unsigned o = (unsigned)f2bf(v[0]) | ((unsigned)f2bf(v[1]) << 16);
        int step = n0 >> 5, w = n0 & 31, q = w >> 3, j = w & 7;
        int sgrp = b >> 4, l15 = b & 15;
        size_t tq = (size_t)(step * 4 + sgrp) * 64 + q * 16 + l15;
        *(unsigned*)(Xf + tq * 8 + j) = o;
    } else {
        int j = (bi - 208) * 256 + threadIdx.x;  // 0..2047
        float m = 0.f;
        #pragma unroll
        for (int c = 0; c < CMCH; c++) m = fmaxf(m, cm[c * NBC + j]);
        cmr[j] = m;
    }
}

// Node 4: GEMM2 monolithic-K (32 blocks, RING=8) with fused epilogue:
// bias + sigmoid + *cmr, LDS-transposed coalesced out stores.
__global__ __launch_bounds__(256) void gemm2_k(
    const float* __restrict__ W2, const unsigned short* __restrict__ Xf,
    const float* __restrict__ b2, const float* __restrict__ cmr,
    float* __restrict__ out)
{
    __shared__ float lds[4 * 4096];              // 64 KB ring; reused for transpose
    int tid = threadIdx.x, lane = tid & 63, wid = tid >> 6;
    int j0 = blockIdx.x * 64;
    int n0 = j0 + wid * 16;
    floatx4 acc[4];
    gemm_ring<KST2, 8>(W2, Xf, acc, NBC, (unsigned)(K2 * NBC - 4),
                       n0, 0, lane, lds + wid * 4096);
    int q = lane >> 4, l15 = lane & 15;
    __syncthreads();                             // all waves done with rings
    #pragma unroll
    for (int s = 0; s < 4; s++) {
        #pragma unroll
        for (int rr = 0; rr < 4; rr++) {
            int j = n0 + q * 4 + rr;
            float v = acc[s][rr] + b2[j];
            v = (1.0f / (1.0f + expf(-v))) * cmr[j];
            lds[(wid * 16 + q * 4 + rr) * 65 + s * 16 + l15] = v;
        }
    }
    __syncthreads();
    #pragma unroll
    for (int e = 0; e < 16; e++) {
        int lin = e * 256 + tid;                 // b-major, j-minor
        int b   = lin >> 6;
        int jj  = lin & 63;
        out[(size_t)b * NBC + j0 + jj] = lds[jj * 65 + b];
    }
}

extern "C" void kernel_launch(void* const* d_in, const int* in_sizes, int n_in,
                              void* d_out, int out_size, void* d_ws, size_t ws_size,
                              hipStream_t stream) {
    const float* gos  = (const float*)d_in[0];
    const float* expx = (const float*)d_in[1];
    const float* W1   = (const float*)d_in[2];
    const float* b1   = (const float*)d_in[3];
    const float* W2   = (const float*)d_in[4];
    const float* b2   = (const float*)d_in[5];
    const float* hpo  = (const float*)d_in[6];
    float* out = (float*)d_out;

    // workspace layout (16B-aligned offsets)
    char* ws = (char*)d_ws;
    unsigned short* gosBf = (unsigned short*)ws;                   // 1,310,720
    unsigned short* Xf    = (unsigned short*)(ws + 1310720);       //   212,992
    float* cm     = (float*)(ws + 1523712);                        //   262,144
    float* cmr    = (float*)(ws + 1785856);                        //     8,192
    float* hpre_p = (float*)(ws + 1794048);                        // 20*393,216 = 7,864,320
    // total ~9.7 MB

    // 1) build gosBf | hpo colmax
    prep_k<<<576, 256, 0, stream>>>(gos, gosBf, hpo, cm);

    // 2) GEMM1 partials (ring core, XCD-clustered)
    gemm1_k<<<480, 256, 0, stream>>>(W1, gosBf, hpre_p);

    // 3) reduce partials + bias + gelu + concat -> Xf | reduce cm -> cmr
    combine1<<<216, 256, 0, stream>>>(hpre_p, b1, expx, Xf, cm, cmr);

    // 4) GEMM2 monolithic + fused sigmoid*cmr epilogue -> out
    gemm2_k<<<32, 256, 0, stream>>>(W2, Xf, b2, cmr, out);
}

// Round 9
// 159.044 us; speedup vs baseline: 1.0944x; 1.0944x over previous
//
#include <hip/hip_runtime.h>
#include <math.h>

// R9: R8 chain (4 kernels) with gemm2 parallelism fixed: 128 blocks x 16
// cols, K split across the block's 4 waves (13 ring-steps each), LDS
// cross-wave reduce, fused bias+sigmoid+*cmr epilogue, float4 stores.
// R8's 32-block monolithic gemm2 used only 32 CUs (~0.8 TB/s) -> +20us.

// Problem constants
#define B64 64
#define IN_SH 10000
#define EXP_SH 53
#define HID 1500
#define NPAD1 1536
#define NBC 2048
#define K2 1553
#define KS1 20              // gemm1 K-chunks: 24 coltiles x 20 = 480 blocks
#define KST1 16             // 16 steps of 32 -> kchunk 512 (20*512=10240)
#define KC2 13              // gemm2: 13 steps/wave x 4 waves = 52 (1664 >= 1553)
#define CMCH 32
#define ACC1 (NPAD1 * 64)   // floats per gemm1 partial

using short8  = __attribute__((ext_vector_type(8))) short;
using floatx4 = __attribute__((ext_vector_type(4))) float;
using uintx4  = __attribute__((ext_vector_type(4))) unsigned int;

__device__ __forceinline__ unsigned short f2bf(float f) {
    unsigned u = __float_as_uint(f);
    u += 0x7fffu + ((u >> 16) & 1u);   // RNE
    return (unsigned short)(u >> 16);
}

// ---- async global->LDS staging (16B/lane; LDS dest = uniform base + lane*16)
typedef __attribute__((address_space(3))) void lds_v;
typedef __attribute__((address_space(1))) const void glb_v;
__device__ __forceinline__ void gll16(const float* g, float* l) {
    __builtin_amdgcn_global_load_lds((glb_v*)g, (lds_v*)l, 16, 0, 0);
}

// counted vmcnt with memory clobber (pins loads/LDS reads across it)
#define WVS(n) asm volatile("s_waitcnt vmcnt(" #n ")" ::: "memory")
template<int N> __device__ __forceinline__ void waitv() {
    if constexpr (N >= 44)      WVS(44);
    else if constexpr (N >= 40) WVS(40);
    else if constexpr (N >= 36) WVS(36);
    else if constexpr (N >= 32) WVS(32);
    else if constexpr (N >= 28) WVS(28);
    else if constexpr (N >= 24) WVS(24);
    else if constexpr (N >= 20) WVS(20);
    else if constexpr (N >= 16) WVS(16);
    else if constexpr (N >= 12) WVS(12);
    else if constexpr (N >= 10) WVS(10);
    else if constexpr (N >= 8)  WVS(8);
    else if constexpr (N >= 6)  WVS(6);
    else if constexpr (N >= 4)  WVS(4);
    else if constexpr (N >= 2)  WVS(2);
    else                        WVS(0);
}

// VMEM ops issued after STAGE(st)'s 2 glls, up to the wait at iter st.
// Emission: prologue S0..S(RING-1), B0, B1; body st: [S(st+RING)] [B(st+2)].
constexpr int after_ops(int KS, int RING, int st) {
    int n = 0;
    if (st < RING) {
        n += 2 * (RING - 1 - st) + 8;
        for (int k = 0; k < st; k++)
            n += (k + RING < KS ? 2 : 0) + (k + 2 < KS ? 4 : 0);
    } else {
        n += (st - RING + 2 < KS ? 4 : 0);
        for (int k = st - RING + 1; k < st; k++)
            n += (k + RING < KS ? 2 : 0) + (k + 2 < KS ? 4 : 0);
    }
    return n;
}

template<int KS, int RING, int ST>
__device__ __forceinline__ void gstep(
    const float* __restrict__ W, const unsigned short* __restrict__ bf,
    float* __restrict__ ldsw, floatx4 (&acc)[4], uintx4 (&bv)[3][4],
    unsigned wbase, unsigned stepInc, unsigned halfInc, unsigned maxoff,
    int q, int l15)
{
    if constexpr (ST < KS) {
        constexpr int AO = after_ops(KS, RING, ST);
        waitv<(AO > 6 ? AO - 6 : 0)>();              // slot ST data is in LDS
        const float* lb = ldsw + (ST % RING) * 512;
        short8 af;
        #pragma unroll
        for (int j = 0; j < 8; j++)
            af[j] = (short)f2bf(lb[(q * 8 + j) * 16 + l15]);
        if constexpr (ST + RING < KS) {              // re-stage slot
            unsigned o0 = wbase + (unsigned)(ST + RING) * stepInc;
            unsigned o1 = o0 + halfInc;
            if (o0 > maxoff) o0 = maxoff;
            if (o1 > maxoff) o1 = maxoff;
            gll16(W + o0, ldsw + ((ST + RING) % RING) * 512);
            gll16(W + o1, ldsw + ((ST + RING) % RING) * 512 + 256);
        }
        if constexpr (ST + 2 < KS) {                 // B prefetch distance 2
            #pragma unroll
            for (int s = 0; s < 4; s++)
                bv[(ST + 2) % 3][s] =
                    *(const uintx4*)(bf + (size_t)((ST + 2) * 4 + s) * 512);
        }
        #pragma unroll
        for (int s = 0; s < 4; s++) {
            short8 b8 = __builtin_bit_cast(short8, bv[ST % 3][s]);
            acc[s] = __builtin_amdgcn_mfma_f32_16x16x32_bf16(af, b8, acc[s], 0, 0, 0);
        }
        gstep<KS, RING, ST + 1>(W, bf, ldsw, acc, bv, wbase, stepInc, halfInc,
                                maxoff, q, l15);
    }
}

// Wave-scoped ring GEMM: 16 cols x KS*32 k-rows into acc. LDS ring of RING
// 2KB slots staged via global_load_lds; OOB by address clamp (garbage rows
// multiply zero-padded B fragments; garbage cols land in padding).
template<int KS, int RING>
__device__ __forceinline__ void gemm_ring(
    const float* __restrict__ W, const unsigned short* __restrict__ Bfc,
    floatx4 (&acc)[4], int ldw, unsigned maxoff, int n0, int k0,
    int lane, float* __restrict__ ldsw)
{
    const int q = lane >> 4, l15 = lane & 15;
    const int r = lane >> 2, c4 = (lane & 3) * 4;
    unsigned wbase = (unsigned)((k0 + r) * ldw + n0 + c4);
    const unsigned stepInc = 32u * (unsigned)ldw;
    const unsigned halfInc = 16u * (unsigned)ldw;

    #pragma unroll
    for (int st = 0; st < RING; st++) {              // prologue: RING stages
        unsigned o0 = wbase + (unsigned)st * stepInc;
        unsigned o1 = o0 + halfInc;
        if (o0 > maxoff) o0 = maxoff;
        if (o1 > maxoff) o1 = maxoff;
        gll16(W + o0, ldsw + st * 512);
        gll16(W + o1, ldsw + st * 512 + 256);
    }
    const unsigned short* bf = Bfc + (size_t)lane * 8;
    uintx4 bv[3][4];
    #pragma unroll
    for (int k = 0; k < 2; k++) {                    // B0, B1
        #pragma unroll
        for (int s = 0; s < 4; s++)
            bv[k][s] = *(const uintx4*)(bf + (size_t)(k * 4 + s) * 512);
    }
    #pragma unroll
    for (int s = 0; s < 4; s++) acc[s] = (floatx4){0.f, 0.f, 0.f, 0.f};

    gstep<KS, RING, 0>(W, bf, ldsw, acc, bv, wbase, stepInc, halfInc, maxoff, q, l15);
}

// Node 1: [0,320) build gosBf | [320,576) hpo colmax chunks
__global__ __launch_bounds__(256) void prep_k(
    const float* __restrict__ g, unsigned short* __restrict__ gosBf,
    const float* __restrict__ M, float* __restrict__ cm)
{
    int bi = blockIdx.x;
    if (bi < 320) {
        int t    = bi * 256 + threadIdx.x;   // [0, 81920)
        int lane = t & 63;
        int sgrp = (t >> 6) & 3;
        int step = t >> 8;                   // [0, 320)
        int q    = lane >> 4;
        int l15  = lane & 15;
        int b    = sgrp * 16 + l15;
        int k0   = step * 32 + q * 8;
        const float* p = g + (size_t)b * IN_SH + k0;
        unsigned int o[4];
        #pragma unroll
        for (int i = 0; i < 4; i++) {
            float lo = (k0 + 2 * i     < IN_SH) ? p[2 * i]     : 0.f;
            float hi = (k0 + 2 * i + 1 < IN_SH) ? p[2 * i + 1] : 0.f;
            o[i] = (unsigned)f2bf(lo) | ((unsigned)f2bf(hi) << 16);
        }
        uintx4 v; v.x = o[0]; v.y = o[1]; v.z = o[2]; v.w = o[3];
        *(uintx4*)(gosBf + (size_t)t * 8) = v;
    } else {
        int u  = bi - 320;                   // [0, 256)
        int j  = (u & 7) * 256 + threadIdx.x;
        int i0 = (u >> 3) * 64;
        float m = 0.0f;
        #pragma unroll 16
        for (int i = i0; i < i0 + 64; i++)
            m = fmaxf(m, M[(size_t)i * NBC + j]);
        cm[(u >> 3) * NBC + j] = m;
    }
}

// Node 2: GEMM1 partials (480 blocks, ring core, XCD-clustered by-chunks)
__global__ __launch_bounds__(256, 4) void gemm1_k(
    const float* __restrict__ W1, const unsigned short* __restrict__ gosBf,
    float* __restrict__ hpre_p)
{
    __shared__ float lds[4 * 2048];
    int bi  = blockIdx.x;                    // [0, 480)
    int swz = (bi & 7) * 60 + (bi >> 3);     // bijective (480 = 8*60): same-by
    int bx  = swz % 24;                      // blocks cluster on one XCD
    int by  = swz / 24;
    int wid = threadIdx.x >> 6;
    int lane = threadIdx.x & 63;
    floatx4 acc[4];
    gemm_ring<KST1, 4>(W1, gosBf + (size_t)by * (KST1 * 4) * 512, acc, HID,
                       (unsigned)(IN_SH * HID - 4),
                       bx * 64 + wid * 16, by * (KST1 * 32),
                       lane, lds + wid * 2048);
    int q = lane >> 4, l15 = lane & 15;
    int nrow = bx * 64 + wid * 16 + q * 4;
    float* pbuf = hpre_p + (size_t)by * ACC1;
    #pragma unroll
    for (int s = 0; s < 4; s++) {
        #pragma unroll
        for (int rr = 0; rr < 4; rr++)
            pbuf[(size_t)(nrow + rr) * 64 + s * 16 + l15] = acc[s][rr];
    }
}

// Node 3: [0,208) reduce 20 partials + bias + GELU + concat -> Xf (coalesced,
// 40 independent streams); [208,216) reduce cm -> cmr.
__global__ __launch_bounds__(256) void combine1(
    const float* __restrict__ hpre_p, const float* __restrict__ b1,
    const float* __restrict__ expx, unsigned short* __restrict__ Xf,
    const float* __restrict__ cm, float* __restrict__ cmr)
{
    int bi = blockIdx.x;
    if (bi < 208) {
        int idx = bi * 256 + threadIdx.x;        // [0, 53248)
        int b   = idx & 63;
        int n0  = (idx >> 6) * 2;                // even n in [0, 1664)
        float v[2];
        #pragma unroll
        for (int e = 0; e < 2; e++) {
            int n = n0 + e;
            float x = 0.f;
            if (n < HID) {
                const float* p = hpre_p + (size_t)n * 64 + b;
                float a0 = 0.f, a1 = 0.f, a2 = 0.f, a3 = 0.f;
                #pragma unroll
                for (int ks = 0; ks < KS1; ks += 4) {
                    a0 += p[(size_t)ks * ACC1];
                    a1 += p[(size_t)(ks + 1) * ACC1];
                    a2 += p[(size_t)(ks + 2) * ACC1];
                    a3 += p[(size_t)(ks + 3) * ACC1];
                }
                float s = b1[n] + ((a0 + a1) + (a2 + a3));
                x = 0.5f * s * (1.0f + erff(s * 0.70710678118654752f));
            } else if (n < HID + EXP_SH) {
                x = expx[b * EXP_SH + (n - HID)];
            }
            v[e] = x;
        }
        unsigned o = (unsigned)f2bf(v[0]) | ((unsigned)f2bf(v[1]) << 16);
        int step = n0 >> 5, w = n0 & 31, q = w >> 3, j = w & 7;
        int sgrp = b >> 4, l15 = b & 15;
        size_t tq = (size_t)(step * 4 + sgrp) * 64 + q * 16 + l15;
        *(unsigned*)(Xf + tq * 8 + j) = o;
    } else {
        int j = (bi - 208) * 256 + threadIdx.x;  // 0..2047
        float m = 0.f;
        #pragma unroll
        for (int c = 0; c < CMCH; c++) m = fmaxf(m, cm[c * NBC + j]);
        cmr[j] = m;
    }
}

// Node 4: GEMM2 fused (128 blocks x 16 cols). K split across the block's 4
// waves (13 ring-steps each); LDS cross-wave reduce; bias+sigmoid+*cmr;
// coalesced float4 stores. XCD-swizzled so each XCD owns a contiguous
// 256-col slab of W2.
__global__ __launch_bounds__(256) void gemm2f_k(
    const float* __restrict__ W2, const unsigned short* __restrict__ Xf,
    const float* __restrict__ b2, const float* __restrict__ cmr,
    float* __restrict__ out)
{
    __shared__ float lds[4 * 2048];              // 32 KB: rings, then acc dump
    int tid = threadIdx.x, lane = tid & 63, wid = tid >> 6;
    int bi  = blockIdx.x;                        // [0, 128)
    int n0  = ((bi & 7) * 16 + (bi >> 3)) * 16;  // XCD-contiguous col tiles
    floatx4 acc[4];
    gemm_ring<KC2, 4>(W2, Xf + (size_t)(wid * KC2 * 4) * 512, acc, NBC,
                      (unsigned)(K2 * NBC - 4), n0, wid * KC2 * 32,
                      lane, lds + wid * 2048);
    __syncthreads();                             // rings fully consumed
    #pragma unroll
    for (int s = 0; s < 4; s++) {
        #pragma unroll
        for (int rr = 0; rr < 4; rr++)
            lds[wid * 1024 + lane * 16 + s * 4 + rr] = acc[s][rr];
    }
    __syncthreads();
    // thread t -> batch b = t>>2, cols j4 = (t&3)*4 .. +3; sum 4 waves
    int b = tid >> 2, j4 = (tid & 3) * 4;
    int s = b >> 4, l15 = b & 15;
    floatx4 v;
    #pragma unroll
    for (int e = 0; e < 4; e++) {
        int j = j4 + e;                          // 0..15
        int q = j >> 2, rr = j & 3;
        int flat = (q * 16 + l15) * 16 + s * 4 + rr;
        float x = lds[flat] + lds[1024 + flat] + lds[2048 + flat] + lds[3072 + flat];
        x += b2[n0 + j];
        v[e] = (1.0f / (1.0f + expf(-x))) * cmr[n0 + j];
    }
    *(floatx4*)(out + (size_t)b * NBC + n0 + j4) = v;
}

extern "C" void kernel_launch(void* const* d_in, const int* in_sizes, int n_in,
                              void* d_out, int out_size, void* d_ws, size_t ws_size,
                              hipStream_t stream) {
    const float* gos  = (const float*)d_in[0];
    const float* expx = (const float*)d_in[1];
    const float* W1   = (const float*)d_in[2];
    const float* b1   = (const float*)d_in[3];
    const float* W2   = (const float*)d_in[4];
    const float* b2   = (const float*)d_in[5];
    const float* hpo  = (const float*)d_in[6];
    float* out = (float*)d_out;

    // workspace layout (16B-aligned offsets)
    char* ws = (char*)d_ws;
    unsigned short* gosBf = (unsigned short*)ws;                   // 1,310,720
    unsigned short* Xf    = (unsigned short*)(ws + 1310720);       //   212,992
    float* cm     = (float*)(ws + 1523712);                        //   262,144
    float* cmr    = (float*)(ws + 1785856);                        //     8,192
    float* hpre_p = (float*)(ws + 1794048);                        // 20*393,216 = 7,864,320
    // total ~9.7 MB

    // 1) build gosBf | hpo colmax
    prep_k<<<576, 256, 0, stream>>>(gos, gosBf, hpo, cm);

    // 2) GEMM1 partials (ring core, XCD-clustered)
    gemm1_k<<<480, 256, 0, stream>>>(W1, gosBf, hpre_p);

    // 3) reduce partials + bias + gelu + concat -> Xf | reduce cm -> cmr
    combine1<<<216, 256, 0, stream>>>(hpre_p, b1, expx, Xf, cm, cmr);

    // 4) GEMM2 fused (128 blocks, wave K-split + LDS reduce + epilogue)
    gemm2f_k<<<128, 256, 0, stream>>>(W2, Xf, b2, cmr, out);
}

// Round 10
// 158.656 us; speedup vs baseline: 1.0971x; 1.0024x over previous
//
#include <hip/hip_runtime.h>
#include <math.h>

// R10: revert to R7 (measured best, 153.7us) + two low-risk carryovers from
// R8/R9 passing rounds: colmax moved from gemm1's grid into prep_k (stops
// colmax from staggering gemm1's block start), gemm1 XCD-cluster swizzle
// (same-by blocks share gosBf chunk in one XCD L2). gemm2 = R7's 416-block
// split-K + final_k (R8/R9 showed every gemm2 restructure costs 5-20us).

// Problem constants
#define B64 64
#define IN_SH 10000
#define EXP_SH 53
#define HID 1500
#define NPAD1 1536
#define NBC 2048
#define K2 1553
#define KS1 20              // gemm1 K-chunks: 24 coltiles x 20 = 480 blocks
#define KST1 16             // 16 steps of 32 -> kchunk 512 (20*512=10240)
#define KS2 13              // 13*128 = 1664 >= 1553
#define KST2 4              // kchunk 128
#define CMCH 32
#define ACC1 (NPAD1 * 64)   // floats per gemm1 partial
#define ACC2 (NBC * 64)     // floats per gemm2 partial

using short8  = __attribute__((ext_vector_type(8))) short;
using floatx4 = __attribute__((ext_vector_type(4))) float;
using uintx4  = __attribute__((ext_vector_type(4))) unsigned int;

__device__ __forceinline__ unsigned short f2bf(float f) {
    unsigned u = __float_as_uint(f);
    u += 0x7fffu + ((u >> 16) & 1u);   // RNE
    return (unsigned short)(u >> 16);
}

// ---- async global->LDS staging (16B/lane; LDS dest = uniform base + lane*16)
typedef __attribute__((address_space(3))) void lds_v;
typedef __attribute__((address_space(1))) const void glb_v;
__device__ __forceinline__ void gll16(const float* g, float* l) {
    __builtin_amdgcn_global_load_lds((glb_v*)g, (lds_v*)l, 16, 0, 0);
}

// counted vmcnt with memory clobber (pins loads/LDS reads across it)
#define WVS(n) asm volatile("s_waitcnt vmcnt(" #n ")" ::: "memory")
template<int N> __device__ __forceinline__ void waitv() {
    if constexpr (N >= 44)      WVS(44);
    else if constexpr (N >= 40) WVS(40);
    else if constexpr (N >= 36) WVS(36);
    else if constexpr (N >= 32) WVS(32);
    else if constexpr (N >= 28) WVS(28);
    else if constexpr (N >= 24) WVS(24);
    else if constexpr (N >= 20) WVS(20);
    else if constexpr (N >= 16) WVS(16);
    else if constexpr (N >= 12) WVS(12);
    else if constexpr (N >= 10) WVS(10);
    else if constexpr (N >= 8)  WVS(8);
    else if constexpr (N >= 6)  WVS(6);
    else if constexpr (N >= 4)  WVS(4);
    else if constexpr (N >= 2)  WVS(2);
    else                        WVS(0);
}

// VMEM ops issued after STAGE(st)'s 2 glls, up to the wait at iter st.
// Emission: prologue S0..S(RING-1), B0, B1; body st: [S(st+RING)] [B(st+2)].
constexpr int after_ops(int KS, int RING, int st) {
    int n = 0;
    if (st < RING) {
        n += 2 * (RING - 1 - st) + 8;
        for (int k = 0; k < st; k++)
            n += (k + RING < KS ? 2 : 0) + (k + 2 < KS ? 4 : 0);
    } else {
        n += (st - RING + 2 < KS ? 4 : 0);
        for (int k = st - RING + 1; k < st; k++)
            n += (k + RING < KS ? 2 : 0) + (k + 2 < KS ? 4 : 0);
    }
    return n;
}

template<int KS, int RING, int ST>
__device__ __forceinline__ void gstep(
    const float* __restrict__ W, const unsigned short* __restrict__ bf,
    float* __restrict__ ldsw, floatx4 (&acc)[4], uintx4 (&bv)[3][4],
    unsigned wbase, unsigned stepInc, unsigned halfInc, unsigned maxoff,
    int q, int l15)
{
    if constexpr (ST < KS) {
        constexpr int AO = after_ops(KS, RING, ST);
        waitv<(AO > 6 ? AO - 6 : 0)>();              // slot ST data is in LDS
        const float* lb = ldsw + (ST % RING) * 512;
        short8 af;
        #pragma unroll
        for (int j = 0; j < 8; j++)
            af[j] = (short)f2bf(lb[(q * 8 + j) * 16 + l15]);
        if constexpr (ST + RING < KS) {              // re-stage slot
            unsigned o0 = wbase + (unsigned)(ST + RING) * stepInc;
            unsigned o1 = o0 + halfInc;
            if (o0 > maxoff) o0 = maxoff;
            if (o1 > maxoff) o1 = maxoff;
            gll16(W + o0, ldsw + ((ST + RING) % RING) * 512);
            gll16(W + o1, ldsw + ((ST + RING) % RING) * 512 + 256);
        }
        if constexpr (ST + 2 < KS) {                 // B prefetch distance 2
            #pragma unroll
            for (int s = 0; s < 4; s++)
                bv[(ST + 2) % 3][s] =
                    *(const uintx4*)(bf + (size_t)((ST + 2) * 4 + s) * 512);
        }
        #pragma unroll
        for (int s = 0; s < 4; s++) {
            short8 b8 = __builtin_bit_cast(short8, bv[ST % 3][s]);
            acc[s] = __builtin_amdgcn_mfma_f32_16x16x32_bf16(af, b8, acc[s], 0, 0, 0);
        }
        gstep<KS, RING, ST + 1>(W, bf, ldsw, acc, bv, wbase, stepInc, halfInc,
                                maxoff, q, l15);
    }
}

// Wave-scoped ring GEMM: 16 cols x KS*32 k-rows into acc. LDS ring of RING
// 2KB slots staged via global_load_lds; OOB by address clamp (garbage rows
// multiply zero-padded B fragments; garbage cols land in padding).
template<int KS, int RING>
__device__ __forceinline__ void gemm_ring(
    const float* __restrict__ W, const unsigned short* __restrict__ Bfc,
    floatx4 (&acc)[4], int ldw, unsigned maxoff, int n0, int k0,
    int lane, float* __restrict__ ldsw)
{
    const int q = lane >> 4, l15 = lane & 15;
    const int r = lane >> 2, c4 = (lane & 3) * 4;
    unsigned wbase = (unsigned)((k0 + r) * ldw + n0 + c4);
    const unsigned stepInc = 32u * (unsigned)ldw;
    const unsigned halfInc = 16u * (unsigned)ldw;

    #pragma unroll
    for (int st = 0; st < RING; st++) {              // prologue: RING stages
        unsigned o0 = wbase + (unsigned)st * stepInc;
        unsigned o1 = o0 + halfInc;
        if (o0 > maxoff) o0 = maxoff;
        if (o1 > maxoff) o1 = maxoff;
        gll16(W + o0, ldsw + st * 512);
        gll16(W + o1, ldsw + st * 512 + 256);
    }
    const unsigned short* bf = Bfc + (size_t)lane * 8;
    uintx4 bv[3][4];
    #pragma unroll
    for (int k = 0; k < 2; k++) {                    // B0, B1
        #pragma unroll
        for (int s = 0; s < 4; s++)
            bv[k][s] = *(const uintx4*)(bf + (size_t)(k * 4 + s) * 512);
    }
    #pragma unroll
    for (int s = 0; s < 4; s++) acc[s] = (floatx4){0.f, 0.f, 0.f, 0.f};

    gstep<KS, RING, 0>(W, bf, ldsw, acc, bv, wbase, stepInc, halfInc, maxoff, q, l15);
}

// Node 1: [0,320) build gosBf | [320,576) hpo colmax chunks (independent
// leaves in one launch; keeps colmax out of gemm1's grid).
__global__ __launch_bounds__(256) void prep_k(
    const float* __restrict__ g, unsigned short* __restrict__ gosBf,
    const float* __restrict__ M, float* __restrict__ cm)
{
    int bi = blockIdx.x;
    if (bi < 320) {
        int t    = bi * 256 + threadIdx.x;   // [0, 81920)
        int lane = t & 63;
        int sgrp = (t >> 6) & 3;
        int step = t >> 8;                   // [0, 320)
        int q    = lane >> 4;
        int l15  = lane & 15;
        int b    = sgrp * 16 + l15;
        int k0   = step * 32 + q * 8;
        const float* p = g + (size_t)b * IN_SH + k0;
        unsigned int o[4];
        #pragma unroll
        for (int i = 0; i < 4; i++) {
            float lo = (k0 + 2 * i     < IN_SH) ? p[2 * i]     : 0.f;
            float hi = (k0 + 2 * i + 1 < IN_SH) ? p[2 * i + 1] : 0.f;
            o[i] = (unsigned)f2bf(lo) | ((unsigned)f2bf(hi) << 16);
        }
        uintx4 v; v.x = o[0]; v.y = o[1]; v.z = o[2]; v.w = o[3];
        *(uintx4*)(gosBf + (size_t)t * 8) = v;
    } else {
        int u  = bi - 320;                   // [0, 256)
        int j  = (u & 7) * 256 + threadIdx.x;
        int i0 = (u >> 3) * 64;
        float m = 0.0f;
        #pragma unroll 16
        for (int i = i0; i < i0 + 64; i++)
            m = fmaxf(m, M[(size_t)i * NBC + j]);
        cm[(u >> 3) * NBC + j] = m;
    }
}

// Node 2: GEMM1 partials (480 blocks, ring core, XCD-clustered by-chunks)
__global__ __launch_bounds__(256, 4) void gemm1_k(
    const float* __restrict__ W1, const unsigned short* __restrict__ gosBf,
    float* __restrict__ hpre_p)
{
    __shared__ float lds[4 * 2048];
    int bi  = blockIdx.x;                    // [0, 480)
    int swz = (bi & 7) * 60 + (bi >> 3);     // bijective (480 = 8*60): same-by
    int bx  = swz % 24;                      // blocks cluster on one XCD
    int by  = swz / 24;
    int wid = threadIdx.x >> 6;
    int lane = threadIdx.x & 63;
    floatx4 acc[4];
    gemm_ring<KST1, 4>(W1, gosBf + (size_t)by * (KST1 * 4) * 512, acc, HID,
                       (unsigned)(IN_SH * HID - 4),
                       bx * 64 + wid * 16, by * (KST1 * 32),
                       lane, lds + wid * 2048);
    int q = lane >> 4, l15 = lane & 15;
    int nrow = bx * 64 + wid * 16 + q * 4;
    float* pbuf = hpre_p + (size_t)by * ACC1;
    #pragma unroll
    for (int s = 0; s < 4; s++) {
        #pragma unroll
        for (int rr = 0; rr < 4; rr++)
            pbuf[(size_t)(nrow + rr) * 64 + s * 16 + l15] = acc[s][rr];
    }
}

// Node 3: [0,208) reduce 20 partials + bias + GELU + concat -> Xf (coalesced,
// 40 independent streams); [208,216) reduce cm -> cmr.
__global__ __launch_bounds__(256) void combine1(
    const float* __restrict__ hpre_p, const float* __restrict__ b1,
    const float* __restrict__ expx, unsigned short* __restrict__ Xf,
    const float* __restrict__ cm, float* __restrict__ cmr)
{
    int bi = blockIdx.x;
    if (bi < 208) {
        int idx = bi * 256 + threadIdx.x;        // [0, 53248)
        int b   = idx & 63;
        int n0  = (idx >> 6) * 2;                // even n in [0, 1664)
        float v[2];
        #pragma unroll
        for (int e = 0; e < 2; e++) {
            int n = n0 + e;
            float x = 0.f;
            if (n < HID) {
                const float* p = hpre_p + (size_t)n * 64 + b;
                float a0 = 0.f, a1 = 0.f, a2 = 0.f, a3 = 0.f;
                #pragma unroll
                for (int ks = 0; ks < KS1; ks += 4) {
                    a0 += p[(size_t)ks * ACC1];
                    a1 += p[(size_t)(ks + 1) * ACC1];
                    a2 += p[(size_t)(ks + 2) * ACC1];
                    a3 += p[(size_t)(ks + 3) * ACC1];
                }
                float s = b1[n] + ((a0 + a1) + (a2 + a3));
                x = 0.5f * s * (1.0f + erff(s * 0.70710678118654752f));
            } else if (n < HID + EXP_SH) {
                x = expx[b * EXP_SH + (n - HID)];
            }
            v[e] = x;
        }
        unsigned o = (unsigned)f2bf(v[0]) | ((unsigned)f2bf(v[1]) << 16);
        int step = n0 >> 5, w = n0 & 31, q = w >> 3, j = w & 7;
        int sgrp = b >> 4, l15 = b & 15;
        size_t tq = (size_t)(step * 4 + sgrp) * 64 + q * 16 + l15;
        *(unsigned*)(Xf + tq * 8 + j) = o;
    } else {
        int j = (bi - 208) * 256 + threadIdx.x;  // 0..2047
        float m = 0.f;
        #pragma unroll
        for (int c = 0; c < CMCH; c++) m = fmaxf(m, cm[c * NBC + j]);
        cmr[j] = m;
    }
}

// Node 4: GEMM2 partials (32x13 = 416 blocks, ring core) — R7's split-K.
__global__ __launch_bounds__(256, 4) void gemm2_k(
    const float* __restrict__ W2, const unsigned short* __restrict__ Xf,
    float* __restrict__ logits_p)
{
    __shared__ float lds[4 * 2048];
    int wid = threadIdx.x >> 6;
    int lane = threadIdx.x & 63;
    int n0 = blockIdx.x * 64 + wid * 16;
    floatx4 acc[4];
    gemm_ring<KST2, 4>(W2, Xf + (size_t)blockIdx.y * (KST2 * 4) * 512, acc,
                       NBC, (unsigned)(K2 * NBC - 4),
                       n0, blockIdx.y * (KST2 * 32), lane, lds + wid * 2048);
    int q = lane >> 4, l15 = lane & 15;
    int nrow = n0 + q * 4;
    float* pbuf = logits_p + (size_t)blockIdx.y * ACC2;
    #pragma unroll
    for (int s = 0; s < 4; s++) {
        #pragma unroll
        for (int rr = 0; rr < 4; rr++)
            pbuf[(size_t)(nrow + rr) * 64 + s * 16 + l15] = acc[s][rr];
    }
}

// Node 5: reduce 13 partials + bias + sigmoid + *cmr -> out (LDS transpose
// for 128B-contiguous out rows)
__global__ __launch_bounds__(256) void final_k(
    const float* __restrict__ logits_p, const float* __restrict__ b2,
    const float* __restrict__ cmr, float* __restrict__ out)
{
    __shared__ float lds[32 * 65];
    int j0  = blockIdx.x * 32;
    int tid = threadIdx.x;
    #pragma unroll
    for (int e = 0; e < 8; e++) {
        int lin = e * 256 + tid;            // j-major, b-minor
        int jj  = lin >> 6;
        int b   = lin & 63;
        int j   = j0 + jj;
        float s = b2[j];
        const float* p = logits_p + (size_t)j * 64 + b;
        #pragma unroll
        for (int ks = 0; ks < KS2; ks++)
            s += p[(size_t)ks * ACC2];
        float sig = 1.0f / (1.0f + expf(-s));
        lds[jj * 65 + b] = sig * cmr[j];
    }
    __syncthreads();
    #pragma unroll
    for (int e = 0; e < 8; e++) {
        int lin = e * 256 + tid;            // b-major, j-minor
        int b   = lin >> 5;
        int jj  = lin & 31;
        out[(size_t)b * NBC + j0 + jj] = lds[jj * 65 + b];
    }
}

extern "C" void kernel_launch(void* const* d_in, const int* in_sizes, int n_in,
                              void* d_out, int out_size, void* d_ws, size_t ws_size,
                              hipStream_t stream) {
    const float* gos  = (const float*)d_in[0];
    const float* expx = (const float*)d_in[1];
    const float* W1   = (const float*)d_in[2];
    const float* b1   = (const float*)d_in[3];
    const float* W2   = (const float*)d_in[4];
    const float* b2   = (const float*)d_in[5];
    const float* hpo  = (const float*)d_in[6];
    float* out = (float*)d_out;

    // workspace layout (16B-aligned offsets)
    char* ws = (char*)d_ws;
    unsigned short* gosBf = (unsigned short*)ws;                   // 1,310,720
    unsigned short* Xf    = (unsigned short*)(ws + 1310720);       //   212,992
    float* cm       = (float*)(ws + 1523712);                      //   262,144
    float* cmr      = (float*)(ws + 1785856);                      //     8,192
    float* hpre_p   = (float*)(ws + 1794048);                      // 20*393,216 = 7,864,320
    float* logits_p = (float*)(ws + 9658368);                      // 13*524,288 = 6,815,744
    // total ~16.5 MB

    // 1) build gosBf | hpo colmax (independent leaves)
    prep_k<<<576, 256, 0, stream>>>(gos, gosBf, hpo, cm);

    // 2) GEMM1 partials (480 blocks, ring core, XCD-clustered)
    gemm1_k<<<480, 256, 0, stream>>>(W1, gosBf, hpre_p);

    // 3) reduce partials + bias + gelu + concat -> Xf | reduce cm -> cmr
    combine1<<<216, 256, 0, stream>>>(hpre_p, b1, expx, Xf, cm, cmr);

    // 4) GEMM2 partials (32x13 blocks, ring core)
    gemm2_k<<<dim3(32, KS2), 256, 0, stream>>>(W2, Xf, logits_p);

    // 5) reduce partials + bias + sigmoid + *cmr -> out
    final_k<<<64, 256, 0, stream>>>(logits_p, b2, cmr, out);
}